// Round 2
// 2267.553 us; speedup vs baseline: 1.9503x; 1.9503x over previous
//
#include <hip/hip_runtime.h>
#include <hip/hip_bf16.h>
#include <cstddef>

#define B_   2
#define S_   2048
#define H_   1024
#define NH_  16
#define D_   64
#define M_   512
#define NTOK (B_*S_)

typedef __hip_bfloat16 bf16;
typedef __attribute__((ext_vector_type(8))) short bf16x8;    // MFMA A/B frag (8 bf16)
typedef __attribute__((ext_vector_type(4))) float f32x4;     // MFMA C/D frag
typedef __attribute__((ext_vector_type(8))) unsigned short ushort8;

__device__ __forceinline__ float toF(bf16 x) { return __bfloat162float(x); }
__device__ __forceinline__ float bfbits2f(unsigned short s) { return __uint_as_float((unsigned)s << 16); }
__device__ __forceinline__ unsigned short f2bfbits(float f) {
    union { bf16 h; unsigned short s; } u; u.h = __float2bfloat16(f); return u.s;
}

// ---------------------------------------------------------------------------
// dtype sniffer: reads 256 fp32-words of Wq. If the buffer actually holds
// bf16 pairs, the LOW 16 bits of each word are a bf16 ~N(0,0.02) whose
// exponent field lands in [100,126] essentially always. If it holds true
// fp32, the low 16 bits are random mantissa -> ~10% hit rate.
// flag = 1 -> buffers are bf16 ; flag = 0 -> fp32.
// ---------------------------------------------------------------------------
__global__ __launch_bounds__(256)
void detect_dtype(const unsigned int* __restrict__ w, int* __restrict__ flag)
{
    __shared__ int cnt[256];
    const int tid = threadIdx.x;
    const unsigned int x = w[tid];
    const unsigned int e0 = (x >> 7) & 0xFFu;
    cnt[tid] = (e0 >= 100u && e0 <= 126u) ? 1 : 0;
    __syncthreads();
    for (int off = 128; off > 0; off >>= 1) {
        if (tid < off) cnt[tid] += cnt[tid + off];
        __syncthreads();
    }
    if (tid == 0) flag[0] = (cnt[0] >= 128) ? 1 : 0;
}

// ---------------------------------------------------------------------------
// convert any input tensor to canonical fp32 in workspace
// ---------------------------------------------------------------------------
__global__ __launch_bounds__(256)
void convert_in(const void* __restrict__ src, float* __restrict__ dst, int n,
                const int* __restrict__ flag)
{
    const int isbf = *flag;
    for (int i = blockIdx.x * 256 + threadIdx.x; i < n; i += gridDim.x * 256)
        dst[i] = isbf ? toF(((const bf16*)src)[i]) : ((const float*)src)[i];
}

// ---------------------------------------------------------------------------
// pack fp32 -> bf16 (2 per u32 word), for MFMA operands
// ---------------------------------------------------------------------------
__global__ __launch_bounds__(256)
void to_bf16_pack(const float* __restrict__ src, unsigned int* __restrict__ dst,
                  int n2)
{
    int i = blockIdx.x * 256 + threadIdx.x;
    const int stride = gridDim.x * 256;
    for (; i < n2; i += stride) {
        const float2 f = ((const float2*)src)[i];
        const unsigned int lo = f2bfbits(f.x);
        const unsigned int hi = f2bfbits(f.y);
        dst[i] = lo | (hi << 16);
    }
}

// ---------------------------------------------------------------------------
// Tiled fp32 GEMM: C[M,N] = A[M,K] @ W[K,N] (+bias); 64x64x16, 256 thr, 4x4.
// ---------------------------------------------------------------------------
__global__ __launch_bounds__(256)
void gemm_tn(const float* __restrict__ A, const float* __restrict__ W,
             const float* __restrict__ bias, float* __restrict__ C,
             int M, int N, int K, int accumulate)
{
    __shared__ float As[16][68];
    __shared__ float Bs[16][68];
    const int tid = threadIdx.x;
    const int tx = tid & 15, ty = tid >> 4;
    const int m0 = blockIdx.y * 64, n0 = blockIdx.x * 64;
    float acc[4][4] = {};

    for (int k0 = 0; k0 < K; k0 += 16) {
        {
            const int r  = tid >> 2;
            const int cg = (tid & 3) * 4;
            const float* ap = A + (size_t)(m0 + r) * K + (k0 + cg);
            #pragma unroll
            for (int j = 0; j < 4; ++j) As[cg + j][r] = ap[j];
        }
        {
            const int r  = tid >> 4;
            const int cg = (tid & 15) * 4;
            const float* wp = W + (size_t)(k0 + r) * N + (n0 + cg);
            #pragma unroll
            for (int j = 0; j < 4; ++j) Bs[r][cg + j] = wp[j];
        }
        __syncthreads();
        #pragma unroll
        for (int kk = 0; kk < 16; ++kk) {
            float a[4], b[4];
            #pragma unroll
            for (int i = 0; i < 4; ++i) a[i] = As[kk][ty * 4 + i];
            #pragma unroll
            for (int j = 0; j < 4; ++j) b[j] = Bs[kk][tx * 4 + j];
            #pragma unroll
            for (int i = 0; i < 4; ++i)
                #pragma unroll
                for (int j = 0; j < 4; ++j)
                    acc[i][j] += a[i] * b[j];
        }
        __syncthreads();
    }

    #pragma unroll
    for (int i = 0; i < 4; ++i) {
        const int row = m0 + ty * 4 + i;
        #pragma unroll
        for (int j = 0; j < 4; ++j) {
            const int col = n0 + tx * 4 + j;
            float v = acc[i][j];
            if (bias) v += bias[col];
            const size_t idx = (size_t)row * N + col;
            if (accumulate) C[idx] += v; else C[idx] = v;
        }
    }
}

// ---------------------------------------------------------------------------
// med logits: out[b,s,t] = sum_m mq[b,s,m]*mk[b,t,m]
// ---------------------------------------------------------------------------
__global__ __launch_bounds__(256)
void med_logits(const float* __restrict__ mq, const float* __restrict__ mk,
                float* __restrict__ out)
{
    const int b = blockIdx.z;
    const float* A  = mq + (size_t)b * S_ * M_;
    const float* Bm = mk + (size_t)b * S_ * M_;
    __shared__ float As[16][68];
    __shared__ float Bs[16][68];
    const int tid = threadIdx.x;
    const int tx = tid & 15, ty = tid >> 4;
    const int m0 = blockIdx.y * 64, n0 = blockIdx.x * 64;
    float acc[4][4] = {};

    for (int k0 = 0; k0 < M_; k0 += 16) {
        const int r  = tid >> 2;
        const int cg = (tid & 3) * 4;
        const float* ap = A  + (size_t)(m0 + r) * M_ + (k0 + cg);
        const float* bp = Bm + (size_t)(n0 + r) * M_ + (k0 + cg);
        #pragma unroll
        for (int j = 0; j < 4; ++j) { As[cg + j][r] = ap[j]; Bs[cg + j][r] = bp[j]; }
        __syncthreads();
        #pragma unroll
        for (int kk = 0; kk < 16; ++kk) {
            float a[4], b[4];
            #pragma unroll
            for (int i = 0; i < 4; ++i) a[i] = As[kk][ty * 4 + i];
            #pragma unroll
            for (int j = 0; j < 4; ++j) b[j] = Bs[kk][tx * 4 + j];
            #pragma unroll
            for (int i = 0; i < 4; ++i)
                #pragma unroll
                for (int j = 0; j < 4; ++j)
                    acc[i][j] += a[i] * b[j];
        }
        __syncthreads();
    }
    #pragma unroll
    for (int i = 0; i < 4; ++i)
        #pragma unroll
        for (int j = 0; j < 4; ++j)
            out[(size_t)b * S_ * S_ + (size_t)(m0 + ty * 4 + i) * S_ + (n0 + tx * 4 + j)]
                = acc[i][j];
}

// ---------------------------------------------------------------------------
// in-place row softmax (fp32), one block per row of S_ columns
// ---------------------------------------------------------------------------
__global__ __launch_bounds__(256)
void row_softmax(float* __restrict__ x)
{
    float* p = x + (size_t)blockIdx.x * S_;
    __shared__ float red[256];
    const int tid = threadIdx.x;

    float m = -1e30f;
    for (int i = tid; i < S_; i += 256) m = fmaxf(m, p[i]);
    red[tid] = m; __syncthreads();
    for (int off = 128; off > 0; off >>= 1) {
        if (tid < off) red[tid] = fmaxf(red[tid], red[tid + off]);
        __syncthreads();
    }
    const float mx = red[0];
    __syncthreads();

    float s = 0.f;
    for (int i = tid; i < S_; i += 256) {
        float e = __expf(fmaxf(p[i] - mx, -80.f));
        p[i] = e; s += e;
    }
    red[tid] = s; __syncthreads();
    for (int off = 128; off > 0; off >>= 1) {
        if (tid < off) red[tid] += red[tid + off];
        __syncthreads();
    }
    const float inv = 1.f / fmaxf(red[0], 1e-30f);
    for (int i = tid; i < S_; i += 256) p[i] *= inv;
}

// ---------------------------------------------------------------------------
// scores = (q @ k^T)*0.125 + 0.3*medp, written (dtype-dispatched) into the
// probs region of d_out. MFMA bf16 GEMM, gemm-BT pattern: both operands are
// [rows, D] with contiguous K. 64x64 tile / block, 4 waves (each 32x32),
// no LDS, no barriers.
// A frag: q[s0+wr+(lane&15)][ks*32 + (lane>>4)*8 + 0..7]
// B frag: k[t0+wc+(lane&15)][ks*32 + (lane>>4)*8 + 0..7]
// C/D   : col = lane&15, row = (lane>>4)*4 + reg            [m89/m91-verified]
// ---------------------------------------------------------------------------
__global__ __launch_bounds__(256)
void qk_scores(const bf16* __restrict__ qh, const bf16* __restrict__ kh,
               const float* __restrict__ medp, void* __restrict__ dout,
               const int* __restrict__ flag)
{
    const int isbf = *flag;
    const int bh = blockIdx.z;
    const int b = bh >> 4;
    const int s0 = blockIdx.y * 64;
    const int t0 = blockIdx.x * 64;
    const int tid  = threadIdx.x;
    const int wave = tid >> 6, lane = tid & 63;
    const int wr = (wave >> 1) * 32, wc = (wave & 1) * 32;
    const int lr = lane & 15;
    const int lk = (lane >> 4) * 8;
    const int h  = bh & 15;

    const bf16* qp = qh + (size_t)(b * S_ + s0 + wr + lr) * H_ + h * D_ + lk;
    const bf16* kp = kh + (size_t)(b * S_ + t0 + wc + lr) * H_ + h * D_ + lk;

    f32x4 acc00 = {0.f, 0.f, 0.f, 0.f};
    f32x4 acc01 = acc00, acc10 = acc00, acc11 = acc00;

    #pragma unroll
    for (int ks = 0; ks < 2; ++ks) {
        const int d = ks * 32;
        const bf16x8 a0 = *(const bf16x8*)(qp + d);
        const bf16x8 a1 = *(const bf16x8*)(qp + (size_t)16 * H_ + d);
        const bf16x8 b0 = *(const bf16x8*)(kp + d);
        const bf16x8 b1 = *(const bf16x8*)(kp + (size_t)16 * H_ + d);
        acc00 = __builtin_amdgcn_mfma_f32_16x16x32_bf16(a0, b0, acc00, 0, 0, 0);
        acc01 = __builtin_amdgcn_mfma_f32_16x16x32_bf16(a0, b1, acc01, 0, 0, 0);
        acc10 = __builtin_amdgcn_mfma_f32_16x16x32_bf16(a1, b0, acc10, 0, 0, 0);
        acc11 = __builtin_amdgcn_mfma_f32_16x16x32_bf16(a1, b1, acc11, 0, 0, 0);
    }

    const size_t pbase = (size_t)NTOK * H_ + ((size_t)bh * S_ + s0) * S_ + t0;
    bf16*  ob = (bf16*)dout  + pbase;
    float* of = (float*)dout + pbase;
    const int crow = (lane >> 4) * 4;
    const int ccol = lane & 15;

    #pragma unroll
    for (int ti = 0; ti < 2; ++ti) {
        const f32x4 aT0 = ti ? acc10 : acc00;
        const f32x4 aT1 = ti ? acc11 : acc01;
        #pragma unroll
        for (int r = 0; r < 4; ++r) {
            const int row = wr + ti * 16 + crow + r;
            const float* mrow = medp + ((size_t)b * S_ + s0 + row) * S_ + t0;
            {
                const int col = wc + ccol;
                const float v = aT0[r] * 0.125f + 0.3f * mrow[col];
                if (isbf) ob[(size_t)row * S_ + col] = __float2bfloat16(v);
                else      of[(size_t)row * S_ + col] = v;
            }
            {
                const int col = wc + 16 + ccol;
                const float v = aT1[r] * 0.125f + 0.3f * mrow[col];
                if (isbf) ob[(size_t)row * S_ + col] = __float2bfloat16(v);
                else      of[(size_t)row * S_ + col] = v;
            }
        }
    }
}

// ---------------------------------------------------------------------------
// in-place row softmax on the probs region of d_out (dtype-dispatched).
// One block per row (S_=2048 -> 8 elems/thread, 16B vector loads).
// ---------------------------------------------------------------------------
__global__ __launch_bounds__(256)
void prob_softmax(void* __restrict__ dout, const int* __restrict__ flag)
{
    const int isbf = *flag;
    const int tid = threadIdx.x;
    const size_t base = (size_t)NTOK * H_ + (size_t)blockIdx.x * S_;
    __shared__ float red[256];
    float x[8];
    bf16*  pb = (bf16*)dout  + base;
    float* pf = (float*)dout + base;

    if (isbf) {
        const ushort8 v = *(const ushort8*)(pb + tid * 8);
        #pragma unroll
        for (int j = 0; j < 8; ++j) x[j] = bfbits2f(v[j]);
    } else {
        const float4 f0 = ((const float4*)pf)[tid * 2];
        const float4 f1 = ((const float4*)pf)[tid * 2 + 1];
        x[0] = f0.x; x[1] = f0.y; x[2] = f0.z; x[3] = f0.w;
        x[4] = f1.x; x[5] = f1.y; x[6] = f1.z; x[7] = f1.w;
    }

    float m = x[0];
    #pragma unroll
    for (int j = 1; j < 8; ++j) m = fmaxf(m, x[j]);
    red[tid] = m; __syncthreads();
    for (int off = 128; off > 0; off >>= 1) {
        if (tid < off) red[tid] = fmaxf(red[tid], red[tid + off]);
        __syncthreads();
    }
    const float mx = red[0];
    __syncthreads();

    float s = 0.f;
    #pragma unroll
    for (int j = 0; j < 8; ++j) {
        x[j] = __expf(fmaxf(x[j] - mx, -80.f));
        s += x[j];
    }
    red[tid] = s; __syncthreads();
    for (int off = 128; off > 0; off >>= 1) {
        if (tid < off) red[tid] += red[tid + off];
        __syncthreads();
    }
    const float inv = 1.f / fmaxf(red[0], 1e-30f);

    if (isbf) {
        ushort8 v;
        #pragma unroll
        for (int j = 0; j < 8; ++j) v[j] = f2bfbits(x[j] * inv);
        *(ushort8*)(pb + tid * 8) = v;
    } else {
        float4 f0, f1;
        f0.x = x[0] * inv; f0.y = x[1] * inv; f0.z = x[2] * inv; f0.w = x[3] * inv;
        f1.x = x[4] * inv; f1.y = x[5] * inv; f1.z = x[6] * inv; f1.w = x[7] * inv;
        ((float4*)pf)[tid * 2]     = f0;
        ((float4*)pf)[tid * 2 + 1] = f1;
    }
}

// ---------------------------------------------------------------------------
// ctx = probs @ v  (probs read back from d_out, dtype-dispatched)
// ---------------------------------------------------------------------------
__global__ __launch_bounds__(256)
void pv_gemm(const void* __restrict__ dout, const float* __restrict__ v,
             float* __restrict__ ctx, const int* __restrict__ flag)
{
    const int isbf = *flag;
    const int bh = blockIdx.y;
    const int b = bh >> 4, h = bh & 15;
    const int m0 = blockIdx.x * 64;
    const size_t pbase = (size_t)NTOK * H_ + (size_t)bh * S_ * S_;
    const bf16*  Ab = (const bf16*)dout  + pbase;
    const float* Af = (const float*)dout + pbase;
    const float* Bv = v + (size_t)b * S_ * H_ + h * D_;
    __shared__ float As[16][68];
    __shared__ float Bs[16][68];
    const int tid = threadIdx.x;
    const int tx = tid & 15, ty = tid >> 4;
    float acc[4][4] = {};

    for (int k0 = 0; k0 < S_; k0 += 16) {
        {
            const int r  = tid >> 2;
            const int cg = (tid & 3) * 4;
            const size_t base = (size_t)(m0 + r) * S_ + (k0 + cg);
            #pragma unroll
            for (int j = 0; j < 4; ++j)
                As[cg + j][r] = isbf ? toF(Ab[base + j]) : Af[base + j];
        }
        {
            const int r  = tid >> 4;
            const int cg = (tid & 15) * 4;
            const float* bp = Bv + (size_t)(k0 + r) * H_ + cg;
            #pragma unroll
            for (int j = 0; j < 4; ++j) Bs[r][cg + j] = bp[j];
        }
        __syncthreads();
        #pragma unroll
        for (int kk = 0; kk < 16; ++kk) {
            float a[4], bb[4];
            #pragma unroll
            for (int i = 0; i < 4; ++i) a[i]  = As[kk][ty * 4 + i];
            #pragma unroll
            for (int j = 0; j < 4; ++j) bb[j] = Bs[kk][tx * 4 + j];
            #pragma unroll
            for (int i = 0; i < 4; ++i)
                #pragma unroll
                for (int j = 0; j < 4; ++j)
                    acc[i][j] += a[i] * bb[j];
        }
        __syncthreads();
    }
    #pragma unroll
    for (int i = 0; i < 4; ++i)
        #pragma unroll
        for (int j = 0; j < 4; ++j)
            ctx[(size_t)(b * S_ + m0 + ty * 4 + i) * H_ + h * D_ + tx * 4 + j] = acc[i][j];
}

// ---------------------------------------------------------------------------
// out0 = LayerNorm(f + hs) * g + beta   (dtype-dispatched write)
// ---------------------------------------------------------------------------
__global__ __launch_bounds__(256)
void add_ln(const float* __restrict__ f, const float* __restrict__ hs,
            const float* __restrict__ g, const float* __restrict__ bta,
            void* __restrict__ dout, const int* __restrict__ flag)
{
    const int isbf = *flag;
    const int row = blockIdx.x;
    const int tid = threadIdx.x;
    __shared__ float red[256];
    float x[4];
    #pragma unroll
    for (int i = 0; i < 4; ++i) {
        const int c = tid + i * 256;
        x[i] = f[(size_t)row * H_ + c] + hs[(size_t)row * H_ + c];
    }
    float s = x[0] + x[1] + x[2] + x[3];
    red[tid] = s; __syncthreads();
    for (int off = 128; off > 0; off >>= 1) {
        if (tid < off) red[tid] += red[tid + off];
        __syncthreads();
    }
    const float mu = red[0] * (1.f / (float)H_);
    __syncthreads();

    float vs = 0.f;
    #pragma unroll
    for (int i = 0; i < 4; ++i) { const float d = x[i] - mu; vs += d * d; }
    red[tid] = vs; __syncthreads();
    for (int off = 128; off > 0; off >>= 1) {
        if (tid < off) red[tid] += red[tid + off];
        __syncthreads();
    }
    const float var = red[0] * (1.f / (float)H_);
    const float inv = 1.f / sqrtf(var + 1e-12f);
    bf16*  ob = (bf16*)dout;
    float* of = (float*)dout;
    #pragma unroll
    for (int i = 0; i < 4; ++i) {
        const int c = tid + i * 256;
        const float y = (x[i] - mu) * inv * g[c] + bta[c];
        if (isbf) ob[(size_t)row * H_ + c] = __float2bfloat16(y);
        else      of[(size_t)row * H_ + c] = y;
    }
}

// ---------------------------------------------------------------------------
extern "C" void kernel_launch(void* const* d_in, const int* in_sizes, int n_in,
                              void* d_out, int out_size, void* d_ws, size_t ws_size,
                              hipStream_t stream)
{
    // header: dtype flag
    int* flag = (int*)d_ws;
    float* p = (float*)((char*)d_ws + 256);

    // converted-input fp32 buffers
    float* hs_f  = p; p += (size_t)NTOK * H_;
    float* mc_f  = p; p += (size_t)NTOK * H_;
    float* Wq_f  = p; p += (size_t)H_ * H_;
    float* Wk_f  = p; p += (size_t)H_ * H_;
    float* Wv_f  = p; p += (size_t)H_ * H_;
    float* Wmq_f = p; p += (size_t)H_ * M_;
    float* Wmk_f = p; p += (size_t)H_ * M_;
    float* Wc_f  = p; p += (size_t)H_ * M_;
    float* Wf_f  = p; p += (size_t)(H_ + M_) * H_;
    float* bq_f  = p; p += H_;
    float* bk_f  = p; p += H_;
    float* bv_f  = p; p += H_;
    float* bmq_f = p; p += M_;
    float* bmk_f = p; p += M_;
    float* bc_f  = p; p += M_;
    float* bf_f  = p; p += H_;
    float* lng_f = p; p += H_;
    float* lnb_f = p; p += H_;

    // pipeline fp32 buffers
    float* q    = p; p += (size_t)NTOK * H_;
    float* k    = p; p += (size_t)NTOK * H_;
    float* v    = p; p += (size_t)NTOK * H_;
    float* mq   = p; p += (size_t)NTOK * M_;
    float* mk   = p; p += (size_t)NTOK * M_;
    float* medp = p; p += (size_t)B_ * S_ * S_;
    float* ctx  = p; p += (size_t)NTOK * H_;
    float* clin = p; p += (size_t)NTOK * M_;
    float* fbuf = p; p += (size_t)NTOK * H_;

    // bf16 MFMA operand buffers — ALIAS onto mc_f (16 MB, dead after the mk
    // GEMM which strictly precedes to_bf16_pack in stream order). Keeps the
    // workspace footprint identical to the last known-passing layout.
    bf16* qh = (bf16*)mc_f;
    bf16* kh = (bf16*)(mc_f + (size_t)NTOK * H_ / 2);

    const dim3 blk(256);

    // 1) dtype detection from Wq
    detect_dtype<<<1, blk, 0, stream>>>((const unsigned int*)d_in[2], flag);

    // 2) convert all inputs to fp32
    float* dsts[18] = { hs_f, mc_f, Wq_f, bq_f, Wk_f, bk_f, Wv_f, bv_f,
                        Wmq_f, bmq_f, Wmk_f, bmk_f, Wc_f, bc_f, Wf_f, bf_f,
                        lng_f, lnb_f };
    for (int i = 0; i < 18; ++i) {
        const int n = in_sizes[i];
        const int g = (n + 255) / 256;
        convert_in<<<dim3(g > 1024 ? 1024 : g), blk, 0, stream>>>(d_in[i], dsts[i], n, flag);
    }

    // 3) projections (fp32 tiled GEMMs)
    gemm_tn<<<dim3(16, 64), blk, 0, stream>>>(hs_f, Wq_f, bq_f, q, NTOK, H_, H_, 0);
    gemm_tn<<<dim3(16, 64), blk, 0, stream>>>(hs_f, Wk_f, bk_f, k, NTOK, H_, H_, 0);
    gemm_tn<<<dim3(16, 64), blk, 0, stream>>>(hs_f, Wv_f, bv_f, v, NTOK, H_, H_, 0);
    gemm_tn<<<dim3(8, 64),  blk, 0, stream>>>(hs_f, Wmq_f, bmq_f, mq, NTOK, M_, H_, 0);
    gemm_tn<<<dim3(8, 64),  blk, 0, stream>>>(mc_f, Wmk_f, bmk_f, mk, NTOK, M_, H_, 0);

    // 3b) pack q,k to bf16 for MFMA (mc_f is dead from here on)
    to_bf16_pack<<<dim3(2048), blk, 0, stream>>>(q, (unsigned int*)qh, NTOK * H_ / 2);
    to_bf16_pack<<<dim3(2048), blk, 0, stream>>>(k, (unsigned int*)kh, NTOK * H_ / 2);

    // 4) medical bias path
    med_logits<<<dim3(32, 32, 2), blk, 0, stream>>>(mq, mk, medp);
    row_softmax<<<dim3(B_ * S_), blk, 0, stream>>>(medp);

    // 5) attention scores (MFMA) -> d_out probs region, then in-place softmax
    qk_scores<<<dim3(32, 32, 32), blk, 0, stream>>>(qh, kh, medp, d_out, flag);
    prob_softmax<<<dim3(B_ * NH_ * S_), blk, 0, stream>>>(d_out, flag);

    // 6) ctx = probs @ v
    pv_gemm<<<dim3(32, 32), blk, 0, stream>>>(d_out, v, ctx, flag);

    // 7) clin = ctx@Wc + bc ; fbuf = ctx@Wf_top + clin@Wf_bot + bf
    gemm_tn<<<dim3(8, 64),  blk, 0, stream>>>(ctx, Wc_f, bc_f, clin, NTOK, M_, H_, 0);
    gemm_tn<<<dim3(16, 64), blk, 0, stream>>>(ctx, Wf_f, bf_f, fbuf, NTOK, H_, H_, 0);
    gemm_tn<<<dim3(16, 64), blk, 0, stream>>>(clin, Wf_f + (size_t)H_ * H_, (const float*)nullptr,
                                              fbuf, NTOK, H_, M_, 1);

    // 8) residual + layernorm -> output 0
    add_ln<<<dim3(NTOK), blk, 0, stream>>>(fbuf, hs_f, lng_f, lnb_f, d_out, flag);
}

// Round 3
// 2166.424 us; speedup vs baseline: 2.0413x; 1.0467x over previous
//
#include <hip/hip_runtime.h>
#include <hip/hip_bf16.h>
#include <cstddef>

#define B_   2
#define S_   2048
#define H_   1024
#define NH_  16
#define D_   64
#define M_   512
#define NTOK (B_*S_)

typedef __hip_bfloat16 bf16;
typedef __attribute__((ext_vector_type(8))) short bf16x8;    // MFMA A/B frag (8 bf16)
typedef __attribute__((ext_vector_type(4))) float f32x4;     // MFMA C/D frag
typedef __attribute__((ext_vector_type(8))) unsigned short ushort8;

__device__ __forceinline__ float toF(bf16 x) { return __bfloat162float(x); }
__device__ __forceinline__ float bfbits2f(unsigned short s) { return __uint_as_float((unsigned)s << 16); }
__device__ __forceinline__ unsigned short f2bfbits(float f) {
    union { bf16 h; unsigned short s; } u; u.h = __float2bfloat16(f); return u.s;
}

// ---------------------------------------------------------------------------
// dtype sniffer (flag=1 -> bf16 inputs, flag=0 -> fp32 inputs)
// ---------------------------------------------------------------------------
__global__ __launch_bounds__(256)
void detect_dtype(const unsigned int* __restrict__ w, int* __restrict__ flag)
{
    __shared__ int cnt[256];
    const int tid = threadIdx.x;
    const unsigned int x = w[tid];
    const unsigned int e0 = (x >> 7) & 0xFFu;
    cnt[tid] = (e0 >= 100u && e0 <= 126u) ? 1 : 0;
    __syncthreads();
    for (int off = 128; off > 0; off >>= 1) {
        if (tid < off) cnt[tid] += cnt[tid + off];
        __syncthreads();
    }
    if (tid == 0) flag[0] = (cnt[0] >= 128) ? 1 : 0;
}

// ---------------------------------------------------------------------------
// convert any input tensor to canonical fp32 in workspace (both modes)
// ---------------------------------------------------------------------------
__global__ __launch_bounds__(256)
void convert_in(const void* __restrict__ src, float* __restrict__ dst, int n,
                const int* __restrict__ flag)
{
    const int isbf = *flag;
    for (int i = blockIdx.x * 256 + threadIdx.x; i < n; i += gridDim.x * 256)
        dst[i] = isbf ? toF(((const bf16*)src)[i]) : ((const float*)src)[i];
}

// ---------------------------------------------------------------------------
// pack fp32 -> bf16 pairs (fp32 fallback mode only)
// ---------------------------------------------------------------------------
__global__ __launch_bounds__(256)
void to_bf16_pack(const float* __restrict__ src, unsigned int* __restrict__ dst,
                  int n2, const int* __restrict__ flag)
{
    if (*flag) return;                      // bf16 mode: not needed
    int i = blockIdx.x * 256 + threadIdx.x;
    const int stride = gridDim.x * 256;
    for (; i < n2; i += stride) {
        const float2 f = ((const float2*)src)[i];
        dst[i] = (unsigned)f2bfbits(f.x) | ((unsigned)f2bfbits(f.y) << 16);
    }
}

// ---------------------------------------------------------------------------
// 64x64-tiled bf16 transpose: dst[Nc][Kr] = src[Kr][Nc]   (bf16 mode only)
// ---------------------------------------------------------------------------
__global__ __launch_bounds__(256)
void transpose_bf16(const unsigned short* __restrict__ src,
                    unsigned short* __restrict__ dst,
                    int Kr, int Nc, const int* __restrict__ flag)
{
    if (*flag == 0) return;
    __shared__ unsigned short t[64][72];
    const int k0 = blockIdx.x * 64, n0 = blockIdx.y * 64;
    const int tid = threadIdx.x;
    const int r = tid >> 2, c = (tid & 3) * 16;
    const ushort8 v0 = *(const ushort8*)(src + (size_t)(k0 + r) * Nc + n0 + c);
    const ushort8 v1 = *(const ushort8*)(src + (size_t)(k0 + r) * Nc + n0 + c + 8);
    #pragma unroll
    for (int j = 0; j < 8; ++j) { t[r][c + j] = v0[j]; t[r][c + 8 + j] = v1[j]; }
    __syncthreads();
    ushort8 w0, w1;
    #pragma unroll
    for (int j = 0; j < 8; ++j) { w0[j] = t[c + j][r]; w1[j] = t[c + 8 + j][r]; }
    *(ushort8*)(dst + (size_t)(n0 + r) * Kr + k0 + c)     = w0;
    *(ushort8*)(dst + (size_t)(n0 + r) * Kr + k0 + c + 8) = w1;
}

// ---------------------------------------------------------------------------
// Generic MFMA bf16 GEMM (bf16 mode only).
// C[z][M,N] = A[z][M,K] @ Bt[z][N,K]^T (+bias), out fp32 or bf16.
// 64x64 tile / 4 waves, no LDS. Wave-coalesced frag loads: the 64 lanes of a
// wave cover 16 full 64B cachelines per load group (lane = row(lr) x k(lk)).
// Frag/CD layouts are the m89/m91-verified BT pattern (HW-validated by
// qk_scores in round 2).
// ---------------------------------------------------------------------------
__global__ __launch_bounds__(256)
void gemm_mfma(const bf16* __restrict__ A, const bf16* __restrict__ Bt,
               const float* __restrict__ bias, void* __restrict__ Cv,
               const int* __restrict__ flag, int K,
               int lda, int ldb, int ldc,
               size_t sAz, size_t sBz, size_t sCz, int out_bf16)
{
    if (*flag == 0) return;
    const int z = blockIdx.z;
    const int m0 = blockIdx.y * 64, n0 = blockIdx.x * 64;
    const int tid = threadIdx.x, wave = tid >> 6, lane = tid & 63;
    const int wr = (wave >> 1) * 32, wc = (wave & 1) * 32;
    const int lr = lane & 15, lk = (lane >> 4) * 8;

    const bf16* ap = A  + (size_t)z * sAz + (size_t)(m0 + wr + lr) * lda + lk;
    const bf16* bp = Bt + (size_t)z * sBz + (size_t)(n0 + wc + lr) * ldb + lk;

    f32x4 acc00 = {0.f, 0.f, 0.f, 0.f};
    f32x4 acc01 = acc00, acc10 = acc00, acc11 = acc00;

    for (int k0 = 0; k0 < K; k0 += 64) {
        #pragma unroll
        for (int u = 0; u < 2; ++u) {
            const int d = k0 + u * 32;
            const bf16x8 a0 = *(const bf16x8*)(ap + d);
            const bf16x8 a1 = *(const bf16x8*)(ap + (size_t)16 * lda + d);
            const bf16x8 b0 = *(const bf16x8*)(bp + d);
            const bf16x8 b1 = *(const bf16x8*)(bp + (size_t)16 * ldb + d);
            acc00 = __builtin_amdgcn_mfma_f32_16x16x32_bf16(a0, b0, acc00, 0, 0, 0);
            acc01 = __builtin_amdgcn_mfma_f32_16x16x32_bf16(a0, b1, acc01, 0, 0, 0);
            acc10 = __builtin_amdgcn_mfma_f32_16x16x32_bf16(a1, b0, acc10, 0, 0, 0);
            acc11 = __builtin_amdgcn_mfma_f32_16x16x32_bf16(a1, b1, acc11, 0, 0, 0);
        }
    }

    const int crow = (lane >> 4) * 4, ccol = lane & 15;
    const size_t cbase = (size_t)z * sCz;
    #pragma unroll
    for (int ti = 0; ti < 2; ++ti) {
        const f32x4 A0 = ti ? acc10 : acc00;
        const f32x4 A1 = ti ? acc11 : acc01;
        #pragma unroll
        for (int r = 0; r < 4; ++r) {
            const int row = m0 + wr + ti * 16 + crow + r;
            const int c0 = n0 + wc + ccol;
            const int c1 = c0 + 16;
            float v0 = A0[r], v1 = A1[r];
            if (bias) { v0 += bias[c0]; v1 += bias[c1]; }
            const size_t i0 = cbase + (size_t)row * ldc + c0;
            const size_t i1 = cbase + (size_t)row * ldc + c1;
            if (out_bf16) {
                ((bf16*)Cv)[i0] = __float2bfloat16(v0);
                ((bf16*)Cv)[i1] = __float2bfloat16(v1);
            } else {
                ((float*)Cv)[i0] = v0;
                ((float*)Cv)[i1] = v1;
            }
        }
    }
}

// ---------------------------------------------------------------------------
// pv (bf16 mode): cat[:, 0:1024] = probs(bf16, in d_out) @ v, via vhT.
// Per (b,h): A = probs[bh] [S,S], Bt = vhT rows (h*64+d) [D,S], out into the
// concat buffer cat[b*S+s][h*64+d] (ldc = H_+M_ = 1536).
// ---------------------------------------------------------------------------
__global__ __launch_bounds__(256)
void pv_mfma(const void* __restrict__ dout, const bf16* __restrict__ vhT,
             bf16* __restrict__ cat, const int* __restrict__ flag)
{
    if (*flag == 0) return;
    const int bh = blockIdx.z;
    const int b = bh >> 4, h = bh & 15;
    const int m0 = blockIdx.x * 64;
    const int tid = threadIdx.x, wave = tid >> 6, lane = tid & 63;
    const int wr = (wave >> 1) * 32, wc = (wave & 1) * 32;
    const int lr = lane & 15, lk = (lane >> 4) * 8;

    const bf16* P  = (const bf16*)dout + (size_t)NTOK * H_ + (size_t)bh * S_ * S_;
    const bf16* ap = P + (size_t)(m0 + wr + lr) * S_ + lk;
    const bf16* bp = vhT + (size_t)(h * 64 + wc + lr) * (size_t)NTOK + (size_t)b * S_ + lk;

    f32x4 acc00 = {0.f, 0.f, 0.f, 0.f};
    f32x4 acc01 = acc00, acc10 = acc00, acc11 = acc00;

    for (int k0 = 0; k0 < S_; k0 += 64) {
        #pragma unroll
        for (int u = 0; u < 2; ++u) {
            const int d = k0 + u * 32;
            const bf16x8 a0 = *(const bf16x8*)(ap + d);
            const bf16x8 a1 = *(const bf16x8*)(ap + (size_t)16 * S_ + d);
            const bf16x8 b0 = *(const bf16x8*)(bp + d);
            const bf16x8 b1 = *(const bf16x8*)(bp + (size_t)16 * NTOK + d);
            acc00 = __builtin_amdgcn_mfma_f32_16x16x32_bf16(a0, b0, acc00, 0, 0, 0);
            acc01 = __builtin_amdgcn_mfma_f32_16x16x32_bf16(a0, b1, acc01, 0, 0, 0);
            acc10 = __builtin_amdgcn_mfma_f32_16x16x32_bf16(a1, b0, acc10, 0, 0, 0);
            acc11 = __builtin_amdgcn_mfma_f32_16x16x32_bf16(a1, b1, acc11, 0, 0, 0);
        }
    }

    const int crow = (lane >> 4) * 4, ccol = lane & 15;
    #pragma unroll
    for (int ti = 0; ti < 2; ++ti) {
        const f32x4 A0 = ti ? acc10 : acc00;
        const f32x4 A1 = ti ? acc11 : acc01;
        #pragma unroll
        for (int r = 0; r < 4; ++r) {
            const int rowl = m0 + wr + ti * 16 + crow + r;
            const size_t rbase = (size_t)(b * S_ + rowl) * (H_ + M_) + h * 64;
            cat[rbase + wc + ccol]      = __float2bfloat16(A0[r]);
            cat[rbase + wc + 16 + ccol] = __float2bfloat16(A1[r]);
        }
    }
}

// ---------------------------------------------------------------------------
// Tiled fp32 GEMM (fp32 fallback mode only)
// ---------------------------------------------------------------------------
__global__ __launch_bounds__(256)
void gemm_tn(const float* __restrict__ A, const float* __restrict__ W,
             const float* __restrict__ bias, float* __restrict__ C,
             int M, int N, int K, int accumulate, const int* __restrict__ flag)
{
    if (*flag != 0) return;
    __shared__ float As[16][68];
    __shared__ float Bs[16][68];
    const int tid = threadIdx.x;
    const int tx = tid & 15, ty = tid >> 4;
    const int m0 = blockIdx.y * 64, n0 = blockIdx.x * 64;
    float acc[4][4] = {};

    for (int k0 = 0; k0 < K; k0 += 16) {
        {
            const int r  = tid >> 2;
            const int cg = (tid & 3) * 4;
            const float* ap = A + (size_t)(m0 + r) * K + (k0 + cg);
            #pragma unroll
            for (int j = 0; j < 4; ++j) As[cg + j][r] = ap[j];
        }
        {
            const int r  = tid >> 4;
            const int cg = (tid & 15) * 4;
            const float* wp = W + (size_t)(k0 + r) * N + (n0 + cg);
            #pragma unroll
            for (int j = 0; j < 4; ++j) Bs[r][cg + j] = wp[j];
        }
        __syncthreads();
        #pragma unroll
        for (int kk = 0; kk < 16; ++kk) {
            float a[4], b[4];
            #pragma unroll
            for (int i = 0; i < 4; ++i) a[i] = As[kk][ty * 4 + i];
            #pragma unroll
            for (int j = 0; j < 4; ++j) b[j] = Bs[kk][tx * 4 + j];
            #pragma unroll
            for (int i = 0; i < 4; ++i)
                #pragma unroll
                for (int j = 0; j < 4; ++j)
                    acc[i][j] += a[i] * b[j];
        }
        __syncthreads();
    }

    #pragma unroll
    for (int i = 0; i < 4; ++i) {
        const int row = m0 + ty * 4 + i;
        #pragma unroll
        for (int j = 0; j < 4; ++j) {
            const int col = n0 + tx * 4 + j;
            float v = acc[i][j];
            if (bias) v += bias[col];
            const size_t idx = (size_t)row * N + col;
            if (accumulate) C[idx] += v; else C[idx] = v;
        }
    }
}

// ---------------------------------------------------------------------------
// med logits, scalar (fp32 fallback mode only)
// ---------------------------------------------------------------------------
__global__ __launch_bounds__(256)
void med_logits(const float* __restrict__ mq, const float* __restrict__ mk,
                float* __restrict__ out, const int* __restrict__ flag)
{
    if (*flag != 0) return;
    const int b = blockIdx.z;
    const float* A  = mq + (size_t)b * S_ * M_;
    const float* Bm = mk + (size_t)b * S_ * M_;
    __shared__ float As[16][68];
    __shared__ float Bs[16][68];
    const int tid = threadIdx.x;
    const int tx = tid & 15, ty = tid >> 4;
    const int m0 = blockIdx.y * 64, n0 = blockIdx.x * 64;
    float acc[4][4] = {};

    for (int k0 = 0; k0 < M_; k0 += 16) {
        const int r  = tid >> 2;
        const int cg = (tid & 3) * 4;
        const float* ap = A  + (size_t)(m0 + r) * M_ + (k0 + cg);
        const float* bp = Bm + (size_t)(n0 + r) * M_ + (k0 + cg);
        #pragma unroll
        for (int j = 0; j < 4; ++j) { As[cg + j][r] = ap[j]; Bs[cg + j][r] = bp[j]; }
        __syncthreads();
        #pragma unroll
        for (int kk = 0; kk < 16; ++kk) {
            float a[4], b[4];
            #pragma unroll
            for (int i = 0; i < 4; ++i) a[i] = As[kk][ty * 4 + i];
            #pragma unroll
            for (int j = 0; j < 4; ++j) b[j] = Bs[kk][tx * 4 + j];
            #pragma unroll
            for (int i = 0; i < 4; ++i)
                #pragma unroll
                for (int j = 0; j < 4; ++j)
                    acc[i][j] += a[i] * b[j];
        }
        __syncthreads();
    }
    #pragma unroll
    for (int i = 0; i < 4; ++i)
        #pragma unroll
        for (int j = 0; j < 4; ++j)
            out[(size_t)b * S_ * S_ + (size_t)(m0 + ty * 4 + i) * S_ + (n0 + tx * 4 + j)]
                = acc[i][j];
}

// ---------------------------------------------------------------------------
// in-place fp32 row softmax (fp32 fallback mode only)
// ---------------------------------------------------------------------------
__global__ __launch_bounds__(256)
void row_softmax(float* __restrict__ x, const int* __restrict__ flag)
{
    if (*flag != 0) return;
    float* p = x + (size_t)blockIdx.x * S_;
    __shared__ float red[256];
    const int tid = threadIdx.x;

    float m = -1e30f;
    for (int i = tid; i < S_; i += 256) m = fmaxf(m, p[i]);
    red[tid] = m; __syncthreads();
    for (int off = 128; off > 0; off >>= 1) {
        if (tid < off) red[tid] = fmaxf(red[tid], red[tid + off]);
        __syncthreads();
    }
    const float mx = red[0];
    __syncthreads();

    float s = 0.f;
    for (int i = tid; i < S_; i += 256) {
        float e = __expf(fmaxf(p[i] - mx, -80.f));
        p[i] = e; s += e;
    }
    red[tid] = s; __syncthreads();
    for (int off = 128; off > 0; off >>= 1) {
        if (tid < off) red[tid] += red[tid + off];
        __syncthreads();
    }
    const float inv = 1.f / fmaxf(red[0], 1e-30f);
    for (int i = tid; i < S_; i += 256) p[i] *= inv;
}

// ---------------------------------------------------------------------------
// med softmax fp32 -> bf16 (bf16 mode only): medp_h = softmax(medl rows)
// ---------------------------------------------------------------------------
__global__ __launch_bounds__(256)
void med_softmax_bf16(const float* __restrict__ in, unsigned short* __restrict__ out,
                      const int* __restrict__ flag)
{
    if (*flag == 0) return;
    const int tid = threadIdx.x;
    const float* p = in + (size_t)blockIdx.x * S_;
    unsigned short* o = out + (size_t)blockIdx.x * S_;
    __shared__ float red[256];
    float x[8];
    const float4 f0 = ((const float4*)p)[tid * 2];
    const float4 f1 = ((const float4*)p)[tid * 2 + 1];
    x[0]=f0.x; x[1]=f0.y; x[2]=f0.z; x[3]=f0.w;
    x[4]=f1.x; x[5]=f1.y; x[6]=f1.z; x[7]=f1.w;

    float m = x[0];
    #pragma unroll
    for (int j = 1; j < 8; ++j) m = fmaxf(m, x[j]);
    red[tid] = m; __syncthreads();
    for (int off = 128; off > 0; off >>= 1) {
        if (tid < off) red[tid] = fmaxf(red[tid], red[tid + off]);
        __syncthreads();
    }
    const float mx = red[0];
    __syncthreads();

    float s = 0.f;
    #pragma unroll
    for (int j = 0; j < 8; ++j) { x[j] = __expf(fmaxf(x[j] - mx, -80.f)); s += x[j]; }
    red[tid] = s; __syncthreads();
    for (int off = 128; off > 0; off >>= 1) {
        if (tid < off) red[tid] += red[tid + off];
        __syncthreads();
    }
    const float inv = 1.f / fmaxf(red[0], 1e-30f);
    ushort8 v;
    #pragma unroll
    for (int j = 0; j < 8; ++j) v[j] = f2bfbits(x[j] * inv);
    *(ushort8*)(o + tid * 8) = v;
}

// ---------------------------------------------------------------------------
// scores = (q @ k^T)*0.125 + 0.3*medp -> probs region of d_out (both modes;
// medp read bf16 in bf16 mode, fp32 in fp32 mode).
// ---------------------------------------------------------------------------
__global__ __launch_bounds__(256)
void qk_scores(const bf16* __restrict__ qh, const bf16* __restrict__ kh,
               const float* __restrict__ medf, const unsigned short* __restrict__ medh,
               void* __restrict__ dout, const int* __restrict__ flag)
{
    const int isbf = *flag;
    const int bh = blockIdx.z;
    const int b = bh >> 4;
    const int s0 = blockIdx.y * 64;
    const int t0 = blockIdx.x * 64;
    const int tid  = threadIdx.x;
    const int wave = tid >> 6, lane = tid & 63;
    const int wr = (wave >> 1) * 32, wc = (wave & 1) * 32;
    const int lr = lane & 15;
    const int lk = (lane >> 4) * 8;
    const int h  = bh & 15;

    const bf16* qp = qh + (size_t)(b * S_ + s0 + wr + lr) * H_ + h * D_ + lk;
    const bf16* kp = kh + (size_t)(b * S_ + t0 + wc + lr) * H_ + h * D_ + lk;

    f32x4 acc00 = {0.f, 0.f, 0.f, 0.f};
    f32x4 acc01 = acc00, acc10 = acc00, acc11 = acc00;

    #pragma unroll
    for (int ks = 0; ks < 2; ++ks) {
        const int d = ks * 32;
        const bf16x8 a0 = *(const bf16x8*)(qp + d);
        const bf16x8 a1 = *(const bf16x8*)(qp + (size_t)16 * H_ + d);
        const bf16x8 b0 = *(const bf16x8*)(kp + d);
        const bf16x8 b1 = *(const bf16x8*)(kp + (size_t)16 * H_ + d);
        acc00 = __builtin_amdgcn_mfma_f32_16x16x32_bf16(a0, b0, acc00, 0, 0, 0);
        acc01 = __builtin_amdgcn_mfma_f32_16x16x32_bf16(a0, b1, acc01, 0, 0, 0);
        acc10 = __builtin_amdgcn_mfma_f32_16x16x32_bf16(a1, b0, acc10, 0, 0, 0);
        acc11 = __builtin_amdgcn_mfma_f32_16x16x32_bf16(a1, b1, acc11, 0, 0, 0);
    }

    const size_t pbase = (size_t)NTOK * H_ + ((size_t)bh * S_ + s0) * S_ + t0;
    bf16*  ob = (bf16*)dout  + pbase;
    float* of = (float*)dout + pbase;
    const int crow = (lane >> 4) * 4;
    const int ccol = lane & 15;

    #pragma unroll
    for (int ti = 0; ti < 2; ++ti) {
        const f32x4 aT0 = ti ? acc10 : acc00;
        const f32x4 aT1 = ti ? acc11 : acc01;
        #pragma unroll
        for (int r = 0; r < 4; ++r) {
            const int row = wr + ti * 16 + crow + r;
            const size_t mrow = ((size_t)b * S_ + s0 + row) * S_ + t0;
            {
                const int col = wc + ccol;
                const float mv = isbf ? bfbits2f(medh[mrow + col]) : medf[mrow + col];
                const float v = aT0[r] * 0.125f + 0.3f * mv;
                if (isbf) ob[(size_t)row * S_ + col] = __float2bfloat16(v);
                else      of[(size_t)row * S_ + col] = v;
            }
            {
                const int col = wc + 16 + ccol;
                const float mv = isbf ? bfbits2f(medh[mrow + col]) : medf[mrow + col];
                const float v = aT1[r] * 0.125f + 0.3f * mv;
                if (isbf) ob[(size_t)row * S_ + col] = __float2bfloat16(v);
                else      of[(size_t)row * S_ + col] = v;
            }
        }
    }
}

// ---------------------------------------------------------------------------
// in-place row softmax on probs region of d_out (both modes)
// ---------------------------------------------------------------------------
__global__ __launch_bounds__(256)
void prob_softmax(void* __restrict__ dout, const int* __restrict__ flag)
{
    const int isbf = *flag;
    const int tid = threadIdx.x;
    const size_t base = (size_t)NTOK * H_ + (size_t)blockIdx.x * S_;
    __shared__ float red[256];
    float x[8];
    bf16*  pb = (bf16*)dout  + base;
    float* pf = (float*)dout + base;

    if (isbf) {
        const ushort8 v = *(const ushort8*)(pb + tid * 8);
        #pragma unroll
        for (int j = 0; j < 8; ++j) x[j] = bfbits2f(v[j]);
    } else {
        const float4 f0 = ((const float4*)pf)[tid * 2];
        const float4 f1 = ((const float4*)pf)[tid * 2 + 1];
        x[0] = f0.x; x[1] = f0.y; x[2] = f0.z; x[3] = f0.w;
        x[4] = f1.x; x[5] = f1.y; x[6] = f1.z; x[7] = f1.w;
    }

    float m = x[0];
    #pragma unroll
    for (int j = 1; j < 8; ++j) m = fmaxf(m, x[j]);
    red[tid] = m; __syncthreads();
    for (int off = 128; off > 0; off >>= 1) {
        if (tid < off) red[tid] = fmaxf(red[tid], red[tid + off]);
        __syncthreads();
    }
    const float mx = red[0];
    __syncthreads();

    float s = 0.f;
    #pragma unroll
    for (int j = 0; j < 8; ++j) {
        x[j] = __expf(fmaxf(x[j] - mx, -80.f));
        s += x[j];
    }
    red[tid] = s; __syncthreads();
    for (int off = 128; off > 0; off >>= 1) {
        if (tid < off) red[tid] += red[tid + off];
        __syncthreads();
    }
    const float inv = 1.f / fmaxf(red[0], 1e-30f);

    if (isbf) {
        ushort8 v;
        #pragma unroll
        for (int j = 0; j < 8; ++j) v[j] = f2bfbits(x[j] * inv);
        *(ushort8*)(pb + tid * 8) = v;
    } else {
        float4 f0, f1;
        f0.x = x[0] * inv; f0.y = x[1] * inv; f0.z = x[2] * inv; f0.w = x[3] * inv;
        f1.x = x[4] * inv; f1.y = x[5] * inv; f1.z = x[6] * inv; f1.w = x[7] * inv;
        ((float4*)pf)[tid * 2]     = f0;
        ((float4*)pf)[tid * 2 + 1] = f1;
    }
}

// ---------------------------------------------------------------------------
// scalar pv (fp32 fallback mode only): ctx = probs @ v
// ---------------------------------------------------------------------------
__global__ __launch_bounds__(256)
void pv_gemm(const void* __restrict__ dout, const float* __restrict__ v,
             float* __restrict__ ctx, const int* __restrict__ flag)
{
    if (*flag != 0) return;
    const int bh = blockIdx.y;
    const int b = bh >> 4, h = bh & 15;
    const int m0 = blockIdx.x * 64;
    const size_t pbase = (size_t)NTOK * H_ + (size_t)bh * S_ * S_;
    const float* Af = (const float*)dout + pbase;
    const float* Bv = v + (size_t)b * S_ * H_ + h * D_;
    __shared__ float As[16][68];
    __shared__ float Bs[16][68];
    const int tid = threadIdx.x;
    const int tx = tid & 15, ty = tid >> 4;
    float acc[4][4] = {};

    for (int k0 = 0; k0 < S_; k0 += 16) {
        {
            const int r  = tid >> 2;
            const int cg = (tid & 3) * 4;
            const size_t base = (size_t)(m0 + r) * S_ + (k0 + cg);
            #pragma unroll
            for (int j = 0; j < 4; ++j) As[cg + j][r] = Af[base + j];
        }
        {
            const int r  = tid >> 4;
            const int cg = (tid & 15) * 4;
            const float* bp = Bv + (size_t)(k0 + r) * H_ + cg;
            #pragma unroll
            for (int j = 0; j < 4; ++j) Bs[r][cg + j] = bp[j];
        }
        __syncthreads();
        #pragma unroll
        for (int kk = 0; kk < 16; ++kk) {
            float a[4], bb[4];
            #pragma unroll
            for (int i = 0; i < 4; ++i) a[i]  = As[kk][ty * 4 + i];
            #pragma unroll
            for (int j = 0; j < 4; ++j) bb[j] = Bs[kk][tx * 4 + j];
            #pragma unroll
            for (int i = 0; i < 4; ++i)
                #pragma unroll
                for (int j = 0; j < 4; ++j)
                    acc[i][j] += a[i] * bb[j];
        }
        __syncthreads();
    }
    #pragma unroll
    for (int i = 0; i < 4; ++i)
        #pragma unroll
        for (int j = 0; j < 4; ++j)
            ctx[(size_t)(b * S_ + m0 + ty * 4 + i) * H_ + h * D_ + tx * 4 + j] = acc[i][j];
}

// ---------------------------------------------------------------------------
// out0 = LayerNorm(f + hs) * g + beta   (both modes)
// ---------------------------------------------------------------------------
__global__ __launch_bounds__(256)
void add_ln(const float* __restrict__ f, const float* __restrict__ hs,
            const float* __restrict__ g, const float* __restrict__ bta,
            void* __restrict__ dout, const int* __restrict__ flag)
{
    const int isbf = *flag;
    const int row = blockIdx.x;
    const int tid = threadIdx.x;
    __shared__ float red[256];
    float x[4];
    #pragma unroll
    for (int i = 0; i < 4; ++i) {
        const int c = tid + i * 256;
        x[i] = f[(size_t)row * H_ + c] + hs[(size_t)row * H_ + c];
    }
    float s = x[0] + x[1] + x[2] + x[3];
    red[tid] = s; __syncthreads();
    for (int off = 128; off > 0; off >>= 1) {
        if (tid < off) red[tid] += red[tid + off];
        __syncthreads();
    }
    const float mu = red[0] * (1.f / (float)H_);
    __syncthreads();

    float vs = 0.f;
    #pragma unroll
    for (int i = 0; i < 4; ++i) { const float d = x[i] - mu; vs += d * d; }
    red[tid] = vs; __syncthreads();
    for (int off = 128; off > 0; off >>= 1) {
        if (tid < off) red[tid] += red[tid + off];
        __syncthreads();
    }
    const float var = red[0] * (1.f / (float)H_);
    const float inv = 1.f / sqrtf(var + 1e-12f);
    bf16*  ob = (bf16*)dout;
    float* of = (float*)dout;
    #pragma unroll
    for (int i = 0; i < 4; ++i) {
        const int c = tid + i * 256;
        const float y = (x[i] - mu) * inv * g[c] + bta[c];
        if (isbf) ob[(size_t)row * H_ + c] = __float2bfloat16(y);
        else      of[(size_t)row * H_ + c] = y;
    }
}

// ---------------------------------------------------------------------------
extern "C" void kernel_launch(void* const* d_in, const int* in_sizes, int n_in,
                              void* d_out, int out_size, void* d_ws, size_t ws_size,
                              hipStream_t stream)
{
    // header: dtype flag
    int* flag = (int*)d_ws;
    float* p = (float*)((char*)d_ws + 256);

    // converted-input fp32 buffers
    float* hs_f  = p; p += (size_t)NTOK * H_;
    float* mc_f  = p; p += (size_t)NTOK * H_;
    float* Wq_f  = p; p += (size_t)H_ * H_;
    float* Wk_f  = p; p += (size_t)H_ * H_;
    float* Wv_f  = p; p += (size_t)H_ * H_;
    float* Wmq_f = p; p += (size_t)H_ * M_;
    float* Wmk_f = p; p += (size_t)H_ * M_;
    float* Wc_f  = p; p += (size_t)H_ * M_;
    float* Wf_f  = p; p += (size_t)(H_ + M_) * H_;
    float* bq_f  = p; p += H_;
    float* bk_f  = p; p += H_;
    float* bv_f  = p; p += H_;
    float* bmq_f = p; p += M_;
    float* bmk_f = p; p += M_;
    float* bc_f  = p; p += M_;
    float* bf_f  = p; p += H_;
    float* lng_f = p; p += H_;
    float* lnb_f = p; p += H_;

    // pipeline fp32 buffers (fp32 fallback mode)
    float* q    = p; p += (size_t)NTOK * H_;
    float* k    = p; p += (size_t)NTOK * H_;
    float* v    = p; p += (size_t)NTOK * H_;
    float* mq   = p; p += (size_t)NTOK * M_;
    float* mk   = p; p += (size_t)NTOK * M_;
    float* medp = p; p += (size_t)B_ * S_ * S_;
    float* ctx  = p; p += (size_t)NTOK * H_;
    float* clin = p; p += (size_t)NTOK * M_;
    float* fbuf = p; p += (size_t)NTOK * H_;

    // ---- bf16-mode buffers, ALL aliased onto fp32-mode-only regions (zero
    //      workspace growth vs the known-passing layout) ----
    // qh/kh shared by BOTH modes -> mc_f (dead after converts / mk proj)
    bf16* qh   = (bf16*)mc_f;                                 // 8 MB
    bf16* kh   = (bf16*)mc_f + (size_t)NTOK * H_;             // 8 MB
    // q region (16 MB): vh + vhT
    bf16* vh   = (bf16*)q;                                    // 8 MB
    bf16* vhT  = (bf16*)q + (size_t)NTOK * H_;                // 8 MB
    // v region (16 MB): mqh + mkh + WcT + WfT
    bf16* mqh  = (bf16*)v;                                    // 4 MB
    bf16* mkh  = (bf16*)v + (size_t)NTOK * M_;                // 4 MB
    bf16* WcT  = (bf16*)v + (size_t)2 * NTOK * M_;            // 1 MB  [M_][H_]
    bf16* WfT  = WcT + (size_t)M_ * H_;                       // 3 MB  [H_][H_+M_]
    // mq+mk region (16.78 MB exactly): medp_h bf16 [B,S,S]
    unsigned short* medp_h = (unsigned short*)mq;
    // ctx region (16 MB): cat bf16 [NTOK][H_+M_] (12.6 MB)
    bf16* cat  = (bf16*)ctx;
    // clin region (8 MB exactly): WqT+WkT+WvT+WmqT+WmkT
    bf16* WqT  = (bf16*)clin;                                 // 2 MB [H_][H_]
    bf16* WkT  = WqT + (size_t)H_ * H_;                       // 2 MB
    bf16* WvT  = WkT + (size_t)H_ * H_;                       // 2 MB
    bf16* WmqT = WvT + (size_t)H_ * H_;                       // 1 MB [M_][H_]
    bf16* WmkT = WmqT + (size_t)M_ * H_;                      // 1 MB

    const dim3 blk(256);

    // 1) dtype detection from Wq
    detect_dtype<<<1, blk, 0, stream>>>((const unsigned int*)d_in[2], flag);

    // 2) convert all inputs to fp32 (both modes; bf16 mode needs hs_f/biases/ln)
    float* dsts[18] = { hs_f, mc_f, Wq_f, bq_f, Wk_f, bk_f, Wv_f, bv_f,
                        Wmq_f, bmq_f, Wmk_f, bmk_f, Wc_f, bc_f, Wf_f, bf_f,
                        lng_f, lnb_f };
    for (int i = 0; i < 18; ++i) {
        const int n = in_sizes[i];
        const int g = (n + 255) / 256;
        convert_in<<<dim3(g > 1024 ? 1024 : g), blk, 0, stream>>>(d_in[i], dsts[i], n, flag);
    }

    // 3) [bf16] weight transposes (read raw bf16 inputs directly)
    transpose_bf16<<<dim3(16, 16), blk, 0, stream>>>((const unsigned short*)d_in[2],  (unsigned short*)WqT,  H_, H_, flag);
    transpose_bf16<<<dim3(16, 16), blk, 0, stream>>>((const unsigned short*)d_in[4],  (unsigned short*)WkT,  H_, H_, flag);
    transpose_bf16<<<dim3(16, 16), blk, 0, stream>>>((const unsigned short*)d_in[6],  (unsigned short*)WvT,  H_, H_, flag);
    transpose_bf16<<<dim3(16, 8),  blk, 0, stream>>>((const unsigned short*)d_in[8],  (unsigned short*)WmqT, H_, M_, flag);
    transpose_bf16<<<dim3(16, 8),  blk, 0, stream>>>((const unsigned short*)d_in[10], (unsigned short*)WmkT, H_, M_, flag);
    transpose_bf16<<<dim3(16, 8),  blk, 0, stream>>>((const unsigned short*)d_in[12], (unsigned short*)WcT,  H_, M_, flag);
    transpose_bf16<<<dim3(24, 16), blk, 0, stream>>>((const unsigned short*)d_in[14], (unsigned short*)WfT,  H_ + M_, H_, flag);

    // 4) [bf16] MFMA projections (A = raw bf16 inputs)
    gemm_mfma<<<dim3(16, 64, 1), blk, 0, stream>>>((const bf16*)d_in[0], WqT, bq_f, qh, flag,
                                                   H_, H_, H_, H_, 0, 0, 0, 1);
    gemm_mfma<<<dim3(16, 64, 1), blk, 0, stream>>>((const bf16*)d_in[0], WkT, bk_f, kh, flag,
                                                   H_, H_, H_, H_, 0, 0, 0, 1);
    gemm_mfma<<<dim3(16, 64, 1), blk, 0, stream>>>((const bf16*)d_in[0], WvT, bv_f, vh, flag,
                                                   H_, H_, H_, H_, 0, 0, 0, 1);
    gemm_mfma<<<dim3(8, 64, 1),  blk, 0, stream>>>((const bf16*)d_in[0], WmqT, bmq_f, mqh, flag,
                                                   H_, H_, H_, M_, 0, 0, 0, 1);
    gemm_mfma<<<dim3(8, 64, 1),  blk, 0, stream>>>((const bf16*)d_in[1], WmkT, bmk_f, mkh, flag,
                                                   H_, H_, H_, M_, 0, 0, 0, 1);
    // vh [NTOK][H_] -> vhT [H_][NTOK]
    transpose_bf16<<<dim3(64, 16), blk, 0, stream>>>((const unsigned short*)vh, (unsigned short*)vhT,
                                                     NTOK, H_, flag);

    // 4b) [fp32] legacy projections + packs
    gemm_tn<<<dim3(16, 64), blk, 0, stream>>>(hs_f, Wq_f, bq_f, q, NTOK, H_, H_, 0, flag);
    gemm_tn<<<dim3(16, 64), blk, 0, stream>>>(hs_f, Wk_f, bk_f, k, NTOK, H_, H_, 0, flag);
    gemm_tn<<<dim3(16, 64), blk, 0, stream>>>(hs_f, Wv_f, bv_f, v, NTOK, H_, H_, 0, flag);
    gemm_tn<<<dim3(8, 64),  blk, 0, stream>>>(hs_f, Wmq_f, bmq_f, mq, NTOK, M_, H_, 0, flag);
    gemm_tn<<<dim3(8, 64),  blk, 0, stream>>>(mc_f, Wmk_f, bmk_f, mk, NTOK, M_, H_, 0, flag);
    to_bf16_pack<<<dim3(2048), blk, 0, stream>>>(q, (unsigned int*)qh, NTOK * H_ / 2, flag);
    to_bf16_pack<<<dim3(2048), blk, 0, stream>>>(k, (unsigned int*)kh, NTOK * H_ / 2, flag);

    // 5) medical bias path
    //    [bf16] med logits via MFMA -> medp (fp32), then softmax -> medp_h (bf16)
    gemm_mfma<<<dim3(32, 32, 2), blk, 0, stream>>>(mqh, mkh, (const float*)nullptr, medp, flag,
                                                   M_, M_, M_, S_,
                                                   (size_t)S_ * M_, (size_t)S_ * M_,
                                                   (size_t)S_ * S_, 0);
    med_logits<<<dim3(32, 32, 2), blk, 0, stream>>>(mq, mk, medp, flag);          // [fp32]
    med_softmax_bf16<<<dim3(B_ * S_), blk, 0, stream>>>(medp, medp_h, flag);      // [bf16]
    row_softmax<<<dim3(B_ * S_), blk, 0, stream>>>(medp, flag);                   // [fp32]

    // 6) attention scores + softmax -> probs (output 1)
    qk_scores<<<dim3(32, 32, 32), blk, 0, stream>>>(qh, kh, medp, medp_h, d_out, flag);
    prob_softmax<<<dim3(B_ * NH_ * S_), blk, 0, stream>>>(d_out, flag);

    // 7) ctx = probs @ v
    pv_mfma<<<dim3(32, 1, 32), blk, 0, stream>>>(d_out, vhT, cat, flag);          // [bf16] -> cat[:, :H_]
    pv_gemm<<<dim3(32, 32), blk, 0, stream>>>(d_out, v, ctx, flag);               // [fp32]

    // 8) clin + fused output GEMM
    //    [bf16] clin = cat[:, :H_] @ Wc + bc -> cat[:, H_:H_+M_]
    gemm_mfma<<<dim3(8, 64, 1), blk, 0, stream>>>(cat, WcT, bc_f, cat + H_, flag,
                                                  H_, H_ + M_, H_, H_ + M_, 0, 0, 0, 1);
    //    [bf16] fbuf = cat @ Wf + bf   (K = H_+M_ = 1536, single GEMM)
    gemm_mfma<<<dim3(16, 64, 1), blk, 0, stream>>>(cat, WfT, bf_f, fbuf, flag,
                                                   H_ + M_, H_ + M_, H_ + M_, H_, 0, 0, 0, 0);
    //    [fp32] legacy chain
    gemm_tn<<<dim3(8, 64),  blk, 0, stream>>>(ctx, Wc_f, bc_f, clin, NTOK, M_, H_, 0, flag);
    gemm_tn<<<dim3(16, 64), blk, 0, stream>>>(ctx, Wf_f, bf_f, fbuf, NTOK, H_, H_, 0, flag);
    gemm_tn<<<dim3(16, 64), blk, 0, stream>>>(clin, Wf_f + (size_t)H_ * H_, (const float*)nullptr,
                                              fbuf, NTOK, H_, M_, 1, flag);

    // 9) residual + layernorm -> output 0
    add_ln<<<dim3(NTOK), blk, 0, stream>>>(fbuf, hs_f, lng_f, lnb_f, d_out, flag);
}